// Round 1
// baseline (238.155 us; speedup 1.0000x reference)
//
#include <hip/hip_runtime.h>
#include <math.h>

// loss = ALPHA * mean(level_w * (softplus(x) - x*t))
//      + BETA  * sum_{b,e} relu(sig(x[b,dst]) - sig(x[b,src])) / (B*N)
// (scatter target of the consistency add is irrelevant to the mean)

#define ALPHA_C 1.0f
#define BETA_C  0.5f

constexpr int B = 4096;
constexpr int N = 4096;
constexpr int E = 16384;
constexpr int THREADS = 256;

__global__ __launch_bounds__(64) void init_ws_kernel(float* ws) {
    if (threadIdx.x < 2) ws[threadIdx.x] = 0.0f;
}

__global__ __launch_bounds__(THREADS) void hier_loss_row_kernel(
    const float* __restrict__ outputs,
    const float* __restrict__ targets,
    const float* __restrict__ level_w,
    const int*   __restrict__ edge_src,
    const int*   __restrict__ edge_dst,
    float*       __restrict__ ws)
{
    __shared__ float p_lds[N];      // sigmoid of this row: 16 KB
    __shared__ float red[8];        // 4 waves x {s1, s2}

    const int b   = blockIdx.x;
    const int tid = threadIdx.x;

    const float4* out4 = (const float4*)(outputs + (size_t)b * N);
    const float4* tgt4 = (const float4*)(targets + (size_t)b * N);
    const float4* lw4  = (const float4*)level_w;

    // ---- phase 1: BCE sum + sigmoid into LDS (coalesced float4) ----
    float s1 = 0.0f;
    for (int i = tid; i < N / 4; i += THREADS) {
        float4 x = out4[i];
        float4 t = tgt4[i];
        float4 w = lw4[i];
        float xs[4] = {x.x, x.y, x.z, x.w};
        float ts[4] = {t.x, t.y, t.z, t.w};
        float wv[4] = {w.x, w.y, w.z, w.w};
        float ps[4];
#pragma unroll
        for (int k = 0; k < 4; ++k) {
            float xv = xs[k];
            // stable softplus: max(x,0) + log1p(exp(-|x|))
            float sp = fmaxf(xv, 0.0f) + log1pf(__expf(-fabsf(xv)));
            s1 += wv[k] * (sp - xv * ts[k]);
            ps[k] = 1.0f / (1.0f + __expf(-xv));
        }
        float4 pv = make_float4(ps[0], ps[1], ps[2], ps[3]);
        ((float4*)p_lds)[i] = pv;
    }
    __syncthreads();

    // ---- phase 2: edge consistency sum (edges streamed as int4, L2-resident) ----
    float s2 = 0.0f;
    const int4* es4 = (const int4*)edge_src;
    const int4* ed4 = (const int4*)edge_dst;
    for (int i = tid; i < E / 4; i += THREADS) {
        int4 s = es4[i];
        int4 d = ed4[i];
        s2 += fmaxf(p_lds[d.x] - p_lds[s.x], 0.0f);
        s2 += fmaxf(p_lds[d.y] - p_lds[s.y], 0.0f);
        s2 += fmaxf(p_lds[d.z] - p_lds[s.z], 0.0f);
        s2 += fmaxf(p_lds[d.w] - p_lds[s.w], 0.0f);
    }

    // ---- block reduce (wave64 shuffle, then LDS across 4 waves) ----
#pragma unroll
    for (int off = 32; off > 0; off >>= 1) {
        s1 += __shfl_down(s1, off, 64);
        s2 += __shfl_down(s2, off, 64);
    }
    const int wave = tid >> 6;
    const int lane = tid & 63;
    if (lane == 0) { red[wave] = s1; red[wave + 4] = s2; }
    __syncthreads();
    if (tid == 0) {
        float a = red[0] + red[1] + red[2] + red[3];
        float c = red[4] + red[5] + red[6] + red[7];
        atomicAdd(&ws[0], a);
        atomicAdd(&ws[1], c);
    }
}

__global__ __launch_bounds__(64) void finalize_kernel(const float* __restrict__ ws,
                                                      float* __restrict__ out)
{
    if (threadIdx.x == 0) {
        const float inv = 1.0f / ((float)B * (float)N);
        out[0] = ALPHA_C * ws[0] * inv + BETA_C * ws[1] * inv;
    }
}

extern "C" void kernel_launch(void* const* d_in, const int* in_sizes, int n_in,
                              void* d_out, int out_size, void* d_ws, size_t ws_size,
                              hipStream_t stream) {
    const float* outputs = (const float*)d_in[0];
    const float* targets = (const float*)d_in[1];
    const float* level_w = (const float*)d_in[2];
    const int*   edge_src = (const int*)d_in[3];
    const int*   edge_dst = (const int*)d_in[4];
    float* ws  = (float*)d_ws;
    float* out = (float*)d_out;

    init_ws_kernel<<<1, 64, 0, stream>>>(ws);
    hier_loss_row_kernel<<<B, THREADS, 0, stream>>>(outputs, targets, level_w,
                                                    edge_src, edge_dst, ws);
    finalize_kernel<<<1, 64, 0, stream>>>(ws, out);
}

// Round 2
// 179.609 us; speedup vs baseline: 1.3260x; 1.3260x over previous
//
#include <hip/hip_runtime.h>
#include <math.h>

// loss = ALPHA * mean(level_w * (softplus(x) - x*t))
//      + BETA  * sum_{b,e} relu(sig(x[b,dst]) - sig(x[b,src])) / (B*N)
// (scatter target of the consistency add is irrelevant to the mean)

#define ALPHA_C 1.0f
#define BETA_C  0.5f

constexpr int B = 4096;
constexpr int N = 4096;
constexpr int E = 16384;
constexpr int THREADS = 256;

__global__ __launch_bounds__(64) void init_out_kernel(float* out) {
    if (threadIdx.x == 0) out[0] = 0.0f;
}

__device__ __forceinline__ void fast_sig_sp(float x, float& p, float& sp) {
    // q = exp(-|x|) in (0,1]; both sigmoid and softplus from one exp
    float q = __expf(-fabsf(x));
    float d = 1.0f + q;
    float r = __builtin_amdgcn_rcpf(d);     // ~1 ulp approx reciprocal
    p  = (x >= 0.0f) ? r : q * r;           // sigmoid
    sp = fmaxf(x, 0.0f) + __logf(d);        // softplus = max(x,0)+log(1+q)
}

__global__ __launch_bounds__(THREADS) void hier_loss_row_kernel(
    const float* __restrict__ outputs,
    const float* __restrict__ targets,
    const float* __restrict__ level_w,
    const int*   __restrict__ edge_src,
    const int*   __restrict__ edge_dst,
    float*       __restrict__ out)
{
    __shared__ float p_lds[N];      // sigmoid of this row: 16 KB
    __shared__ float red[8];        // 4 waves x {s1, s2}

    const int b   = blockIdx.x;
    const int tid = threadIdx.x;

    const float4* out4 = (const float4*)(outputs + (size_t)b * N);
    const float4* tgt4 = (const float4*)(targets + (size_t)b * N);
    const float4* lw4  = (const float4*)level_w;

    // ---- phase 1: BCE sum + sigmoid into LDS (coalesced float4) ----
    float s1 = 0.0f;
#pragma unroll
    for (int ii = 0; ii < N / 4 / THREADS; ++ii) {
        int i = tid + ii * THREADS;
        float4 x = out4[i];
        float4 t = tgt4[i];
        float4 w = lw4[i];
        float xs[4] = {x.x, x.y, x.z, x.w};
        float ts[4] = {t.x, t.y, t.z, t.w};
        float wv[4] = {w.x, w.y, w.z, w.w};
        float ps[4];
#pragma unroll
        for (int k = 0; k < 4; ++k) {
            float p, sp;
            fast_sig_sp(xs[k], p, sp);
            s1 = fmaf(wv[k], sp - xs[k] * ts[k], s1);
            ps[k] = p;
        }
        ((float4*)p_lds)[i] = make_float4(ps[0], ps[1], ps[2], ps[3]);
    }
    __syncthreads();

    // ---- phase 2: edge consistency sum (edges streamed as int4, L2-resident) ----
    float s2 = 0.0f;
    const int4* es4 = (const int4*)edge_src;
    const int4* ed4 = (const int4*)edge_dst;
#pragma unroll 4
    for (int i = tid; i < E / 4; i += THREADS) {
        int4 s = es4[i];
        int4 d = ed4[i];
        s2 += fmaxf(p_lds[d.x] - p_lds[s.x], 0.0f);
        s2 += fmaxf(p_lds[d.y] - p_lds[s.y], 0.0f);
        s2 += fmaxf(p_lds[d.z] - p_lds[s.z], 0.0f);
        s2 += fmaxf(p_lds[d.w] - p_lds[s.w], 0.0f);
    }

    // ---- block reduce (wave64 shuffle, then LDS across 4 waves) ----
#pragma unroll
    for (int off = 32; off > 0; off >>= 1) {
        s1 += __shfl_down(s1, off, 64);
        s2 += __shfl_down(s2, off, 64);
    }
    const int wave = tid >> 6;
    const int lane = tid & 63;
    if (lane == 0) { red[wave] = s1; red[wave + 4] = s2; }
    __syncthreads();
    if (tid == 0) {
        float a = red[0] + red[1] + red[2] + red[3];
        float c = red[4] + red[5] + red[6] + red[7];
        const float inv = 1.0f / ((float)B * (float)N);
        atomicAdd(out, (ALPHA_C * a + BETA_C * c) * inv);
    }
}

extern "C" void kernel_launch(void* const* d_in, const int* in_sizes, int n_in,
                              void* d_out, int out_size, void* d_ws, size_t ws_size,
                              hipStream_t stream) {
    const float* outputs = (const float*)d_in[0];
    const float* targets = (const float*)d_in[1];
    const float* level_w = (const float*)d_in[2];
    const int*   edge_src = (const int*)d_in[3];
    const int*   edge_dst = (const int*)d_in[4];
    float* out = (float*)d_out;

    init_out_kernel<<<1, 64, 0, stream>>>(out);
    hier_loss_row_kernel<<<B, THREADS, 0, stream>>>(outputs, targets, level_w,
                                                    edge_src, edge_dst, out);
}

// Round 3
// 162.480 us; speedup vs baseline: 1.4657x; 1.1054x over previous
//
#include <hip/hip_runtime.h>
#include <math.h>

// loss = ALPHA * mean(level_w * (softplus(x) - x*t))
//      + BETA  * sum_{b,e} relu(sig(x[b,dst]) - sig(x[b,src])) / (B*N)
// (scatter target of the consistency add is irrelevant to the mean)
//
// R2: process R=4 rows per block; p stored transposed in LDS as float4
// {p_r0..p_r3} so each edge gather is ONE ds_read_b128 serving 4 rows.

#define ALPHA_C 1.0f
#define BETA_C  0.5f

constexpr int B = 4096;
constexpr int N = 4096;
constexpr int E = 16384;
constexpr int THREADS = 512;
constexpr int R = 4;            // rows per block

__global__ __launch_bounds__(64) void init_out_kernel(float* out) {
    if (threadIdx.x == 0) out[0] = 0.0f;
}

__device__ __forceinline__ void fast_sig_sp(float x, float& p, float& sp) {
    // q = exp(-|x|) in (0,1]; both sigmoid and softplus from one exp
    float q = __expf(-fabsf(x));
    float d = 1.0f + q;
    float r = __builtin_amdgcn_rcpf(d);     // ~1 ulp approx reciprocal
    p  = (x >= 0.0f) ? r : q * r;           // sigmoid
    sp = fmaxf(x, 0.0f) + __logf(d);        // softplus = max(x,0)+log(1+q)
}

__device__ __forceinline__ float edge4(const float4* __restrict__ p, int s, int d) {
    float4 a = p[s];
    float4 c = p[d];
    return fmaxf(c.x - a.x, 0.0f) + fmaxf(c.y - a.y, 0.0f) +
           fmaxf(c.z - a.z, 0.0f) + fmaxf(c.w - a.w, 0.0f);
}

__global__ __launch_bounds__(THREADS) void hier_loss_kernel(
    const float* __restrict__ outputs,
    const float* __restrict__ targets,
    const float* __restrict__ level_w,
    const int*   __restrict__ edge_src,
    const int*   __restrict__ edge_dst,
    float*       __restrict__ out)
{
    __shared__ float4 p_lds[N];     // 64 KB: p_lds[n] = {p(r0..r0+3, n)}

    const int r0  = blockIdx.x * R;
    const int tid = threadIdx.x;

    // ---- phase 1: BCE sum + transposed sigmoid into LDS ----
    float s1 = 0.0f;
#pragma unroll
    for (int j = 0; j < N / THREADS; ++j) {          // 8 iters
        const int n = tid + j * THREADS;
        const float w = level_w[n];
        float pv[R];
#pragma unroll
        for (int r = 0; r < R; ++r) {
            const float x = outputs[(size_t)(r0 + r) * N + n];  // coalesced
            const float t = targets[(size_t)(r0 + r) * N + n];
            float p, sp;
            fast_sig_sp(x, p, sp);
            s1 = fmaf(w, sp - x * t, s1);
            pv[r] = p;
        }
        p_lds[n] = make_float4(pv[0], pv[1], pv[2], pv[3]);  // conflict-free b128
    }
    __syncthreads();

    // ---- phase 2: edge consistency; one b128 gather covers 4 rows ----
    float s2 = 0.0f;
    const int4* es4 = (const int4*)edge_src;
    const int4* ed4 = (const int4*)edge_dst;
#pragma unroll
    for (int j = 0; j < E / 4 / THREADS; ++j) {      // 8 iters
        const int i = tid + j * THREADS;
        const int4 s = es4[i];
        const int4 d = ed4[i];
        s2 += edge4(p_lds, s.x, d.x);
        s2 += edge4(p_lds, s.y, d.y);
        s2 += edge4(p_lds, s.z, d.z);
        s2 += edge4(p_lds, s.w, d.w);
    }

    // ---- block reduce: wave64 shuffle, cross-wave via reused p_lds ----
#pragma unroll
    for (int off = 32; off > 0; off >>= 1) {
        s1 += __shfl_down(s1, off, 64);
        s2 += __shfl_down(s2, off, 64);
    }
    __syncthreads();                     // all phase-2 reads done before reuse
    float* red = (float*)p_lds;
    const int wave = tid >> 6;           // 8 waves
    const int lane = tid & 63;
    if (lane == 0) { red[wave] = s1; red[8 + wave] = s2; }
    __syncthreads();
    if (tid == 0) {
        float a = 0.0f, c = 0.0f;
#pragma unroll
        for (int w = 0; w < 8; ++w) { a += red[w]; c += red[8 + w]; }
        const float inv = 1.0f / ((float)B * (float)N);
        atomicAdd(out, (ALPHA_C * a + BETA_C * c) * inv);
    }
}

extern "C" void kernel_launch(void* const* d_in, const int* in_sizes, int n_in,
                              void* d_out, int out_size, void* d_ws, size_t ws_size,
                              hipStream_t stream) {
    const float* outputs = (const float*)d_in[0];
    const float* targets = (const float*)d_in[1];
    const float* level_w = (const float*)d_in[2];
    const int*   edge_src = (const int*)d_in[3];
    const int*   edge_dst = (const int*)d_in[4];
    float* out = (float*)d_out;

    init_out_kernel<<<1, 64, 0, stream>>>(out);
    hier_loss_kernel<<<B / R, THREADS, 0, stream>>>(outputs, targets, level_w,
                                                    edge_src, edge_dst, out);
}

// Round 4
// 157.862 us; speedup vs baseline: 1.5086x; 1.0293x over previous
//
#include <hip/hip_runtime.h>
#include <math.h>

// loss = ALPHA * mean(level_w * (softplus(x) - x*t))
//      + BETA  * sum_{b,e} relu(sig(x[b,dst]) - sig(x[b,src])) / (B*N)
// (scatter target of the consistency add is irrelevant to the mean)
//
// R3: R=4 rows/block, p transposed in LDS as float4 (one ds_read_b128 serves
// 4 rows per edge endpoint). 1024-thread blocks -> 2 resident blocks/CU
// (128 KB LDS) = 32 waves/CU = 100% occupancy (R2's 512-thr/64KB gave 36%).

#define ALPHA_C 1.0f
#define BETA_C  0.5f

constexpr int B = 4096;
constexpr int N = 4096;
constexpr int E = 16384;
constexpr int THREADS = 1024;
constexpr int R = 4;            // rows per block

__global__ __launch_bounds__(64) void init_out_kernel(float* out) {
    if (threadIdx.x == 0) out[0] = 0.0f;
}

__device__ __forceinline__ void fast_sig_sp(float x, float& p, float& sp) {
    // q = exp(-|x|) in (0,1]; both sigmoid and softplus from one exp
    float q = __expf(-fabsf(x));
    float d = 1.0f + q;
    float r = __builtin_amdgcn_rcpf(d);     // ~1 ulp approx reciprocal
    p  = (x >= 0.0f) ? r : q * r;           // sigmoid
    sp = fmaxf(x, 0.0f) + __logf(d);        // softplus = max(x,0)+log(1+q)
}

__device__ __forceinline__ float edge4(const float4* __restrict__ p, int s, int d) {
    float4 a = p[s];
    float4 c = p[d];
    return fmaxf(c.x - a.x, 0.0f) + fmaxf(c.y - a.y, 0.0f) +
           fmaxf(c.z - a.z, 0.0f) + fmaxf(c.w - a.w, 0.0f);
}

__global__ __launch_bounds__(THREADS) void hier_loss_kernel(
    const float* __restrict__ outputs,
    const float* __restrict__ targets,
    const float* __restrict__ level_w,
    const int*   __restrict__ edge_src,
    const int*   __restrict__ edge_dst,
    float*       __restrict__ out)
{
    __shared__ float4 p_lds[N];     // 64 KB: p_lds[n] = {p(r0..r0+3, n)}

    const int r0  = blockIdx.x * R;
    const int tid = threadIdx.x;

    // ---- phase 1: BCE sum + transposed sigmoid into LDS ----
    float s1 = 0.0f;
#pragma unroll
    for (int j = 0; j < N / THREADS; ++j) {          // 4 iters
        const int n = tid + j * THREADS;
        const float w = level_w[n];
        float pv[R];
#pragma unroll
        for (int r = 0; r < R; ++r) {
            const float x = outputs[(size_t)(r0 + r) * N + n];  // coalesced
            const float t = targets[(size_t)(r0 + r) * N + n];
            float p, sp;
            fast_sig_sp(x, p, sp);
            s1 = fmaf(w, sp - x * t, s1);
            pv[r] = p;
        }
        p_lds[n] = make_float4(pv[0], pv[1], pv[2], pv[3]);  // conflict-free b128
    }
    __syncthreads();

    // ---- phase 2: edge consistency; one b128 gather covers 4 rows ----
    float s2a = 0.0f, s2b = 0.0f;
    const int4* es4 = (const int4*)edge_src;
    const int4* ed4 = (const int4*)edge_dst;
#pragma unroll
    for (int j = 0; j < E / 4 / THREADS; ++j) {      // 4 iters
        const int i = tid + j * THREADS;
        const int4 s = es4[i];
        const int4 d = ed4[i];
        s2a += edge4(p_lds, s.x, d.x);
        s2b += edge4(p_lds, s.y, d.y);
        s2a += edge4(p_lds, s.z, d.z);
        s2b += edge4(p_lds, s.w, d.w);
    }
    float s2 = s2a + s2b;

    // ---- block reduce: wave64 shuffle, cross-wave via reused p_lds ----
#pragma unroll
    for (int off = 32; off > 0; off >>= 1) {
        s1 += __shfl_down(s1, off, 64);
        s2 += __shfl_down(s2, off, 64);
    }
    __syncthreads();                     // all phase-2 reads done before reuse
    float* red = (float*)p_lds;
    const int wave = tid >> 6;           // 16 waves
    const int lane = tid & 63;
    if (lane == 0) { red[wave] = s1; red[16 + wave] = s2; }
    __syncthreads();
    if (tid == 0) {
        float a = 0.0f, c = 0.0f;
#pragma unroll
        for (int w = 0; w < 16; ++w) { a += red[w]; c += red[16 + w]; }
        const float inv = 1.0f / ((float)B * (float)N);
        atomicAdd(out, (ALPHA_C * a + BETA_C * c) * inv);
    }
}

extern "C" void kernel_launch(void* const* d_in, const int* in_sizes, int n_in,
                              void* d_out, int out_size, void* d_ws, size_t ws_size,
                              hipStream_t stream) {
    const float* outputs = (const float*)d_in[0];
    const float* targets = (const float*)d_in[1];
    const float* level_w = (const float*)d_in[2];
    const int*   edge_src = (const int*)d_in[3];
    const int*   edge_dst = (const int*)d_in[4];
    float* out = (float*)d_out;

    init_out_kernel<<<1, 64, 0, stream>>>(out);
    hier_loss_kernel<<<B / R, THREADS, 0, stream>>>(outputs, targets, level_w,
                                                    edge_src, edge_dst, out);
}